// Round 4
// baseline (532.381 us; speedup 1.0000x reference)
//
#include <hip/hip_runtime.h>
#include <math.h>

// LSTM B=8192,T=512,IN=3,H=32,OUT=2 fp32.
// 8 batches/wave, 1024 waves (1 per SIMD). B-frag cols 0-7 = h_hi, cols
// 8-15 = h_lo -> one MFMA computes both hi and lo products; shfl_xor(8)
// folds column halves into full preacts. Lane pair (n, n+8) splits the 8
// units of each (batch, q-group) 4/4, so nonlinearities halve and the c/h
// update stays lane-local. 24 MFMA/step (vs 32), 32 trans/step (vs 64).
// Weights pre-scaled by -log2e (-2log2e for g-gate) -> raw v_exp_f32.

namespace {
constexpr int   kT   = 512;
constexpr float kL2E = 1.44269504088896340736f;
}

typedef __bf16 bf16x8 __attribute__((ext_vector_type(8)));
typedef float  f32x4  __attribute__((ext_vector_type(4)));

union Frag {
    bf16x8 v;
    unsigned short u[8];
    unsigned int   d[4];
};

__device__ __forceinline__ unsigned short bf_rne(float f) {
    unsigned u = __float_as_uint(f);
    u += 0x7fffu + ((u >> 16) & 1u);
    return (unsigned short)(u >> 16);
}
__device__ __forceinline__ float bf_tof(unsigned short h) {
    return __uint_as_float((unsigned)h << 16);
}
__device__ __forceinline__ float fast_exp2(float v) { return __builtin_amdgcn_exp2f(v); }
__device__ __forceinline__ float fast_rcp(float v)  { return __builtin_amdgcn_rcpf(v); }
__device__ __forceinline__ unsigned pck(unsigned short a, unsigned short b) {
    return (unsigned)a | ((unsigned)b << 16);
}

#define MFMA16 __builtin_amdgcn_mfma_f32_16x16x32_bf16

extern "C" __global__ __launch_bounds__(64, 1)
void lstm_fold(const float* __restrict__ x,
               const float* __restrict__ W_ih,
               const float* __restrict__ W_hh,
               const float* __restrict__ b_ih,
               const float* __restrict__ b_hh,
               const float* __restrict__ W_fc,
               const float* __restrict__ b_fc,
               float* __restrict__ out) {
    const int  lane = threadIdx.x & 63;
    const int  n2   = lane & 15;        // B/D column
    const int  q    = lane >> 4;        // quad (k-group / row-group)
    const int  pl   = n2 >> 3;          // 0 = hi-stream col, 1 = lo-stream col
    const int  bat  = n2 & 7;
    const int  b    = blockIdx.x * 8 + bat;
    const bool isLo = (pl != 0);
    const bool isQ0 = (q == 0);
    const unsigned short ONE = 0x3F80;  // bf16 1.0
    const unsigned short Z   = 0;

    // ---- prologue: permuted scaled A-frags ----
    // chunk cc: gate g=cc>>1, part p=cc&1; A row m holds W row
    // R = 32g + 8(m>>2) + 4p + (m&3)  => D row (4q+r) of chunk cc is
    // gate g of unit (8q + 4p + r).
    Frag Ah[8], Al[8], AX[8];
#pragma unroll
    for (int cc = 0; cc < 8; ++cc) {
        const int   g = cc >> 1, p = cc & 1;
        const float s = (g == 2) ? -2.0f * kL2E : -kL2E;
        const int   R = 32 * g + 8 * (n2 >> 2) + 4 * p + (n2 & 3);
#pragma unroll
        for (int j = 0; j < 8; ++j) {
            const float w = W_hh[R * 32 + 8 * q + j] * s;
            const unsigned short hb = bf_rne(w);
            Ah[cc].u[j] = hb;
            Al[cc].u[j] = bf_rne(w - bf_tof(hb));
        }
        // AX (q==0 lanes only): k0-2 Wx_hi, k3 bias_hi, k4-6 Wx_lo, k7 bias_lo
        unsigned short axu[8];
#pragma unroll
        for (int j = 0; j < 8; ++j) axu[j] = 0;
#pragma unroll
        for (int j = 0; j < 3; ++j) {
            const float w = W_ih[R * 3 + j] * s;
            const unsigned short hb = bf_rne(w);
            axu[j]     = hb;
            axu[4 + j] = bf_rne(w - bf_tof(hb));
        }
        {
            const float bias = (b_ih[R] + b_hh[R]) * s;
            const unsigned short bh = bf_rne(bias);
            axu[3] = bh;
            axu[7] = bf_rne(bias - bf_tof(bh));
        }
#pragma unroll
        for (int j = 0; j < 8; ++j) AX[cc].u[j] = isQ0 ? axu[j] : Z;
    }

    const float* xb = x + (size_t)b * kT * 3;

    // ---- state ----
    float cst[4]   = {0.f, 0.f, 0.f, 0.f};
    float hfull[4] = {0.f, 0.f, 0.f, 0.f};
    Frag B1, B3;
#pragma unroll
    for (int j = 0; j < 4; ++j) B1.d[j] = 0;

    // B3 builder from x(t): hi-cols [x_hi,1,x_hi,1], lo-cols [x_lo,0,0,0]
    auto buildB3 = [&](float x0, float x1, float x2) {
        const unsigned short xh0 = bf_rne(x0), xh1 = bf_rne(x1), xh2 = bf_rne(x2);
        const unsigned short xl0 = bf_rne(x0 - bf_tof(xh0));
        const unsigned short xl1 = bf_rne(x1 - bf_tof(xh1));
        const unsigned short xl2 = bf_rne(x2 - bf_tof(xh2));
        const unsigned short a0 = isLo ? xl0 : xh0;
        const unsigned short a1 = isLo ? xl1 : xh1;
        const unsigned short a2 = isLo ? xl2 : xh2;
        const unsigned short a3 = isLo ? Z : ONE;
        B3.d[0] = isQ0 ? pck(a0, a1) : 0u;
        B3.d[1] = isQ0 ? pck(a2, a3) : 0u;
        B3.d[2] = (isQ0 && !isLo) ? pck(xh0, xh1) : 0u;
        B3.d[3] = (isQ0 && !isLo) ? pck(xh2, ONE) : 0u;
    };
    buildB3(xb[0], xb[1], xb[2]);

    for (int t = 0; t < kT; ++t) {
        // ---- 24 MFMA: x-pass, Ah pass, Al pass (chunk-interleaved) ----
        f32x4 acc[8];
#pragma unroll
        for (int cc = 0; cc < 8; ++cc) {
            const f32x4 z = {0.f, 0.f, 0.f, 0.f};
            acc[cc] = MFMA16(AX[cc].v, B3.v, z, 0, 0, 0);
        }
#pragma unroll
        for (int cc = 0; cc < 8; ++cc) acc[cc] = MFMA16(Ah[cc].v, B1.v, acc[cc], 0, 0, 0);
#pragma unroll
        for (int cc = 0; cc < 8; ++cc) acc[cc] = MFMA16(Al[cc].v, B1.v, acc[cc], 0, 0, 0);

        // prefetch next x
        const int   tn  = (t + 1 < kT) ? t + 1 : t;
        const float xn0 = xb[tn * 3 + 0];
        const float xn1 = xb[tn * 3 + 1];
        const float xn2 = xb[tn * 3 + 2];

        // ---- fold column halves + select my part: P[g][r] ----
        float P[4][4];
#pragma unroll
        for (int g = 0; g < 4; ++g) {
#pragma unroll
            for (int r = 0; r < 4; ++r) {
                const float fe = acc[2 * g + 0][r] + __shfl_xor(acc[2 * g + 0][r], 8, 64);
                const float fo = acc[2 * g + 1][r] + __shfl_xor(acc[2 * g + 1][r], 8, 64);
                P[g][r] = isLo ? fo : fe;
            }
        }

        // ---- lane-local c/h update for my 4 units (u = 8q + 4pl + r) ----
        unsigned short hh[4], hl[4];
#pragma unroll
        for (int r = 0; r < 4; ++r) {
            const float Ei = fast_exp2(P[0][r]);
            const float Ef = fast_exp2(P[1][r]);
            float       Eg = fast_exp2(P[2][r]);
            const float Eo = fast_exp2(P[3][r]);
            Eg = fminf(Eg, 1e30f);
            const float sf  = fast_rcp(1.0f + Ef);
            const float dig = fast_rcp((1.0f + Ei) * (1.0f + Eg));
            const float ig  = (1.0f - Eg) * dig;
            const float c   = fmaf(sf, cst[r], ig);
            cst[r] = c;
            float Ec = fast_exp2(c * (-2.0f * kL2E));
            Ec = fminf(Ec, 1e30f);
            const float doc = fast_rcp((1.0f + Eo) * (1.0f + Ec));
            const float h   = (1.0f - Ec) * doc;
            hfull[r] = h;
            hh[r] = bf_rne(h);
            hl[r] = bf_rne(h - bf_tof(hh[r]));
        }

        // ---- exchange with partner lane (lane^8) and assemble next B1 ----
        const unsigned myhi01 = pck(hh[0], hh[1]), myhi23 = pck(hh[2], hh[3]);
        const unsigned mylo01 = pck(hl[0], hl[1]), mylo23 = pck(hl[2], hl[3]);
        const unsigned phi01 = __shfl_xor(myhi01, 8, 64);
        const unsigned phi23 = __shfl_xor(myhi23, 8, 64);
        const unsigned plo01 = __shfl_xor(mylo01, 8, 64);
        const unsigned plo23 = __shfl_xor(mylo23, 8, 64);
        // slots 0-3 = p=0 units, slots 4-7 = p=1 units; hi cols take hi, lo cols lo
        B1.d[0] = isLo ? plo01 : myhi01;
        B1.d[1] = isLo ? plo23 : myhi23;
        B1.d[2] = isLo ? mylo01 : phi01;
        B1.d[3] = isLo ? mylo23 : phi23;

        buildB3(xn0, xn1, xn2);
    }

    // ---- epilogue: out[b][o] = sum_u h_u W_fc[o][u] + b_fc[o] ----
    const int base = 8 * q + 4 * pl;
    float s0 = 0.f, s1 = 0.f;
#pragma unroll
    for (int r = 0; r < 4; ++r) {
        s0 = fmaf(hfull[r], W_fc[base + r], s0);
        s1 = fmaf(hfull[r], W_fc[32 + base + r], s1);
    }
    s0 += __shfl_xor(s0, 8, 64); s0 += __shfl_xor(s0, 16, 64); s0 += __shfl_xor(s0, 32, 64);
    s1 += __shfl_xor(s1, 8, 64); s1 += __shfl_xor(s1, 16, 64); s1 += __shfl_xor(s1, 32, 64);
    if (lane < 8) {
        out[(size_t)b * 2 + 0] = s0 + b_fc[0];
        out[(size_t)b * 2 + 1] = s1 + b_fc[1];
    }
}

extern "C" void kernel_launch(void* const* d_in, const int* in_sizes, int n_in,
                              void* d_out, int out_size, void* d_ws, size_t ws_size,
                              hipStream_t stream) {
    const float* x    = (const float*)d_in[0];
    const float* W_ih = (const float*)d_in[1];
    const float* W_hh = (const float*)d_in[2];
    const float* b_ih = (const float*)d_in[3];
    const float* b_hh = (const float*)d_in[4];
    const float* W_fc = (const float*)d_in[5];
    const float* b_fc = (const float*)d_in[6];
    float* out = (float*)d_out;

    const int batch = in_sizes[0] / (kT * 3);   // 8192
    dim3 grid(batch / 8);                       // 1024 blocks, 1 wave each
    dim3 block(64);
    hipLaunchKernelGGL(lstm_fold, grid, block, 0, stream,
                       x, W_ih, W_hh, b_ih, b_hh, W_fc, b_fc, out);
}

// Round 5
// 526.866 us; speedup vs baseline: 1.0105x; 1.0105x over previous
//
#include <hip/hip_runtime.h>
#include <math.h>

// LSTM B=8192,T=512,IN=3,H=32,OUT=2 fp32.
// 4 batches/wave, 2048 waves = 2 per SIMD (512-thr blocks, 8 waves, 1 block/CU)
// -> MFMA of one wave overlaps VALU of the other (m114). Batches replicated in
// all 4 column-quadrants (identical D -> no fold); the 4 replicas split the 8
// units of each q-group 4-ways -> 2 units/lane, 16 trans/lane/step.
// x@W_ih + bias computed EXACTLY in fp32 VALU and injected via the MFMA
// C-operand (only the lane's consumed D-slots) -> no x-MFMAs: 24 MFMA/step.
// h hi/lo reassembly: 6 shfl_xor + cndmasks. Zero LDS, zero barriers.
// Weights pre-scaled by -log2e (-2log2e for g) -> raw v_exp_f32.

namespace {
constexpr int   kT   = 512;
constexpr float kL2E = 1.44269504088896340736f;
}

typedef __bf16 bf16x8 __attribute__((ext_vector_type(8)));
typedef float  f32x4  __attribute__((ext_vector_type(4)));

union Frag {
    bf16x8 v;
    unsigned short u[8];
    unsigned int   d[4];
};

__device__ __forceinline__ unsigned short bf_rne(float f) {
    unsigned u = __float_as_uint(f);
    u += 0x7fffu + ((u >> 16) & 1u);
    return (unsigned short)(u >> 16);
}
__device__ __forceinline__ float bf_tof(unsigned short h) {
    return __uint_as_float((unsigned)h << 16);
}
__device__ __forceinline__ float fast_exp2(float v) { return __builtin_amdgcn_exp2f(v); }
__device__ __forceinline__ float fast_rcp(float v)  { return __builtin_amdgcn_rcpf(v); }
__device__ __forceinline__ unsigned pck(unsigned short a, unsigned short b) {
    return (unsigned)a | ((unsigned)b << 16);
}

#define MFMA16 __builtin_amdgcn_mfma_f32_16x16x32_bf16

extern "C" __global__ __launch_bounds__(512, 2)
void lstm_dual(const float* __restrict__ x,
               const float* __restrict__ W_ih,
               const float* __restrict__ W_hh,
               const float* __restrict__ b_ih,
               const float* __restrict__ b_hh,
               const float* __restrict__ W_fc,
               const float* __restrict__ b_fc,
               float* __restrict__ out) {
    const int lane = threadIdx.x & 63;
    const int wv   = threadIdx.x >> 6;          // wave in block, 0..7
    const int grp  = blockIdx.x * 8 + wv;       // global wave id, 0..2047
    const int n    = lane & 15;                 // B/D column
    const int q    = lane >> 4;                 // quad
    const int bat  = n & 3;                     // batch within wave's 4
    const int rh   = (n >> 2) & 1;              // reg-pair selector
    const int p    = (n >> 3) & 1;              // chunk-parity selector
    const int b    = grp * 4 + bat;             // global batch
    const bool prh = (rh != 0);
    const bool pp1 = (p != 0);

    // ---- A-frags: permuted scaled W_hh (hi/lo). Chunk cc (g=cc>>1, pc=cc&1):
    // A row m holds W row R = 32g + 8(m>>2) + 4pc + (m&3); so D row 4q+r of
    // chunk cc = gate g, unit u = 8q + 4pc + r.
    Frag Ah[8], Al[8];
#pragma unroll
    for (int cc = 0; cc < 8; ++cc) {
        const int   g  = cc >> 1, pc = cc & 1;
        const float s  = (g == 2) ? -2.0f * kL2E : -kL2E;
        const int   R  = 32 * g + 8 * (n >> 2) + 4 * pc + (n & 3);
#pragma unroll
        for (int j = 0; j < 8; ++j) {
            const float w = W_hh[R * 32 + 8 * q + j] * s;
            const unsigned short hb = bf_rne(w);
            Ah[cc].u[j] = hb;
            Al[cc].u[j] = bf_rne(w - bf_tof(hb));
        }
    }

    // ---- per-lane x-path constants for my 8 consumed (gate, unit) slots ----
    // my units: u0 = 8q + 4p + 2rh, u1 = u0 + 1
    const int u0 = 8 * q + 4 * p + 2 * rh;
    float xw[4][2][3], xbias[4][2];
#pragma unroll
    for (int g = 0; g < 4; ++g) {
        const float s = (g == 2) ? -2.0f * kL2E : -kL2E;
#pragma unroll
        for (int j2 = 0; j2 < 2; ++j2) {
            const int R = 32 * g + u0 + j2;
#pragma unroll
            for (int k = 0; k < 3; ++k) xw[g][j2][k] = W_ih[R * 3 + k] * s;
            xbias[g][j2] = (b_ih[R] + b_hh[R]) * s;
        }
    }

    const float* xb = x + (size_t)b * kT * 3;

    float cst[2]   = {0.f, 0.f};
    float hfull[2] = {0.f, 0.f};
    Frag Bh, Bl;
#pragma unroll
    for (int j = 0; j < 4; ++j) { Bh.d[j] = 0; Bl.d[j] = 0; }

    float xc0 = xb[0], xc1 = xb[1], xc2 = xb[2];

    for (int t = 0; t < kT; ++t) {
        // ---- exact fp32 x-preacts for my consumed slots ----
        float xp[4][2];
#pragma unroll
        for (int g = 0; g < 4; ++g)
#pragma unroll
            for (int j2 = 0; j2 < 2; ++j2)
                xp[g][j2] = fmaf(xc0, xw[g][j2][0],
                            fmaf(xc1, xw[g][j2][1],
                            fmaf(xc2, xw[g][j2][2], xbias[g][j2])));

        // ---- 24 MFMA: (C=xpre) + Ah*Bh, Al*Bh, Ah*Bl ----
        f32x4 acc[8];
#pragma unroll
        for (int cc = 0; cc < 8; ++cc) {
            const int  g    = cc >> 1;
            const bool mine = ((cc & 1) == p);
            f32x4 C;
            C[0] = (mine && !prh) ? xp[g][0] : 0.f;
            C[1] = (mine && !prh) ? xp[g][1] : 0.f;
            C[2] = (mine &&  prh) ? xp[g][0] : 0.f;
            C[3] = (mine &&  prh) ? xp[g][1] : 0.f;
            acc[cc] = MFMA16(Ah[cc].v, Bh.v, C, 0, 0, 0);
        }
#pragma unroll
        for (int cc = 0; cc < 8; ++cc) acc[cc] = MFMA16(Al[cc].v, Bh.v, acc[cc], 0, 0, 0);
#pragma unroll
        for (int cc = 0; cc < 8; ++cc) acc[cc] = MFMA16(Ah[cc].v, Bl.v, acc[cc], 0, 0, 0);

        // prefetch next x (one step of slack before use)
        const int tn = (t + 1 < kT) ? t + 1 : t;
        const float xn0 = xb[tn * 3 + 0];
        const float xn1 = xb[tn * 3 + 1];
        const float xn2 = xb[tn * 3 + 2];

        // ---- select my 8 preacts: r = 2rh + j2, chunk = 2g + p ----
        float P[4][2];
#pragma unroll
        for (int g = 0; g < 4; ++g) {
#pragma unroll
            for (int j2 = 0; j2 < 2; ++j2) {
                const float ve = prh ? acc[2 * g + 0][2 + j2] : acc[2 * g + 0][j2];
                const float vo = prh ? acc[2 * g + 1][2 + j2] : acc[2 * g + 1][j2];
                P[g][j2] = pp1 ? vo : ve;
            }
        }

        // ---- c/h update for my 2 units ----
        unsigned short hh[2], hl[2];
#pragma unroll
        for (int j2 = 0; j2 < 2; ++j2) {
            const float Ei = fast_exp2(P[0][j2]);
            const float Ef = fast_exp2(P[1][j2]);
            float       Eg = fast_exp2(P[2][j2]);
            const float Eo = fast_exp2(P[3][j2]);
            Eg = fminf(Eg, 1e30f);
            const float sf  = fast_rcp(1.0f + Ef);
            const float dig = fast_rcp((1.0f + Ei) * (1.0f + Eg));
            const float ig  = (1.0f - Eg) * dig;
            const float c   = fmaf(sf, cst[j2], ig);
            cst[j2] = c;
            float Ec = fast_exp2(c * (-2.0f * kL2E));
            Ec = fminf(Ec, 1e30f);
            const float doc = fast_rcp((1.0f + Eo) * (1.0f + Ec));
            const float h   = (1.0f - Ec) * doc;
            hfull[j2] = h;
            hh[j2] = bf_rne(h);
            hl[j2] = bf_rne(h - bf_tof(hh[j2]));
        }

        // ---- assemble next B-frags: gather 4 dwords across the replica quad ----
        // my dword = d[s], s = 2p + rh; xor4 flips rh, xor8 flips p
        const unsigned myhi = pck(hh[0], hh[1]);
        const unsigned mylo = pck(hl[0], hl[1]);
        const unsigned othi = __shfl_xor(myhi, 4, 64);
        const unsigned otlo = __shfl_xor(mylo, 4, 64);
        const unsigned eA = prh ? othi : myhi;   // d[2p]
        const unsigned eB = prh ? myhi : othi;   // d[2p+1]
        const unsigned eC = prh ? otlo : mylo;
        const unsigned eD = prh ? mylo : otlo;
        const unsigned fA = __shfl_xor(eA, 8, 64);
        const unsigned fB = __shfl_xor(eB, 8, 64);
        const unsigned fC = __shfl_xor(eC, 8, 64);
        const unsigned fD = __shfl_xor(eD, 8, 64);
        Bh.d[0] = pp1 ? fA : eA;
        Bh.d[1] = pp1 ? fB : eB;
        Bh.d[2] = pp1 ? eA : fA;
        Bh.d[3] = pp1 ? eB : fB;
        Bl.d[0] = pp1 ? fC : eC;
        Bl.d[1] = pp1 ? fD : eD;
        Bl.d[2] = pp1 ? eC : fC;
        Bl.d[3] = pp1 ? eD : fD;

        xc0 = xn0; xc1 = xn1; xc2 = xn2;
    }

    // ---- epilogue: out[b][o] = sum_u h_u W_fc[o][u] + b_fc[o] ----
    float s0 = 0.f, s1 = 0.f;
#pragma unroll
    for (int j2 = 0; j2 < 2; ++j2) {
        const int u = u0 + j2;
        s0 = fmaf(hfull[j2], W_fc[u], s0);
        s1 = fmaf(hfull[j2], W_fc[32 + u], s1);
    }
    // reduce over replica bits (2,3) and quad bits (4,5)
    s0 += __shfl_xor(s0, 4, 64);  s1 += __shfl_xor(s1, 4, 64);
    s0 += __shfl_xor(s0, 8, 64);  s1 += __shfl_xor(s1, 8, 64);
    s0 += __shfl_xor(s0, 16, 64); s1 += __shfl_xor(s1, 16, 64);
    s0 += __shfl_xor(s0, 32, 64); s1 += __shfl_xor(s1, 32, 64);
    if (lane < 4) {
        out[(size_t)b * 2 + 0] = s0 + b_fc[0];
        out[(size_t)b * 2 + 1] = s1 + b_fc[1];
    }
}

extern "C" void kernel_launch(void* const* d_in, const int* in_sizes, int n_in,
                              void* d_out, int out_size, void* d_ws, size_t ws_size,
                              hipStream_t stream) {
    const float* x    = (const float*)d_in[0];
    const float* W_ih = (const float*)d_in[1];
    const float* W_hh = (const float*)d_in[2];
    const float* b_ih = (const float*)d_in[3];
    const float* b_hh = (const float*)d_in[4];
    const float* W_fc = (const float*)d_in[5];
    const float* b_fc = (const float*)d_in[6];
    float* out = (float*)d_out;

    const int batch = in_sizes[0] / (kT * 3);   // 8192
    dim3 grid(batch / 32);                      // 256 blocks (1 per CU)
    dim3 block(512);                            // 8 waves -> 2 per SIMD
    hipLaunchKernelGGL(lstm_dual, grid, block, 0, stream,
                       x, W_ih, W_hh, b_ih, b_hh, W_fc, b_fc, out);
}